// Round 4
// baseline (89.005 us; speedup 1.0000x reference)
//
#include <hip/hip_runtime.h>

// Problem constants: N_SUPPORT=10, N_QUERY=25, N_CLASS=2
// ns_all = 20, nq_all = 50, D = 128, F = 512
#define NS_ALL 20
#define NQ_ALL 50
#define DIM0   128
#define FEAT   512

// Output: (50*20, 128, 1024) fp32.  out[q,s,d,0:512]=sup[s,d,:], [512:1024]=qry[q,d,:]
//
// R4: tile (QT,ST) = (10,10) — minimizes staged-rows per emitted-row
// (1/QT + 1/ST = 0.20 vs 0.30 for (5,10)). Reads 77 MB -> 51 MB,
// stage:emit overhead 15% -> 10%. LDS 40 KB -> 4 blocks/CU.

typedef float f32x4 __attribute__((ext_vector_type(4)));

#define QT 10           // q's per block
#define ST 10           // s's per block
#define F4 (FEAT / 4)   // 128 float4 per input row
// LDS: [0, ST*F4) = sup rows, [ST*F4, (ST+QT)*F4) = qry rows
#define LDS_F4 ((QT + ST) * F4)   // 2560 f4 = 40 KB

__global__ __launch_bounds__(256) void concat_pairs_lds_kernel(
    const f32x4* __restrict__ x4, f32x4* __restrict__ out4)
{
    const f32x4* sup4 = x4;                              // 20*128*128 f4
    const f32x4* qry4 = x4 + NS_ALL * DIM0 * F4;         // + 327680

    __shared__ f32x4 lds[LDS_F4];                        // 40 KB

    const int tid = threadIdx.x;
    // bid = (qt * 2 + st) * 128 + d   (d fastest -> concurrent blocks write
    // adjacent 4 KB output rows)
    const int bid = blockIdx.x;
    const int d   = bid & 127;
    const int tb  = bid >> 7;          // 0..9
    const int st  = tb & 1;            // 0..1   (s-tile)
    const int qt  = tb >> 1;           // 0..4   (q-tile)

    // ---- stage phase: 2560 f4 = ST sup rows + QT qry rows ----
    for (int j = tid; j < LDS_F4; j += 256) {
        f32x4 v;
        if (j < ST * F4) {
            int s   = j >> 7;          // row within s-tile
            int off = j & 127;
            v = sup4[((st * ST + s) * DIM0 + d) * F4 + off];
        } else {
            int jj  = j - ST * F4;
            int q   = jj >> 7;
            int off = jj & 127;
            v = qry4[((qt * QT + q) * DIM0 + d) * F4 + off];
        }
        lds[j] = v;
    }
    __syncthreads();

    // ---- emit phase: QT*ST = 100 output rows of 256 f4 each ----
    // thread t supplies f4 #t of the row: t<128 -> sup half, else qry half
    const f32x4* src = (tid < F4) ? &lds[tid] : &lds[ST * F4 + (tid - F4)];
    #pragma unroll
    for (int r = 0; r < QT * ST; ++r) {
        int q = r / ST;                // 0..9
        int s = r - q * ST;            // 0..9
        f32x4 v = (tid < F4) ? src[s * F4] : src[q * F4];
        int pair = (qt * QT + q) * NS_ALL + (st * ST + s);
        // out f4 index: (pair*128 + d)*256 + tid
        __builtin_nontemporal_store(v, &out4[((pair << 7) + d) * 256 + tid]);
    }
}

extern "C" void kernel_launch(void* const* d_in, const int* in_sizes, int n_in,
                              void* d_out, int out_size, void* d_ws, size_t ws_size,
                              hipStream_t stream) {
    const f32x4* x4 = (const f32x4*)d_in[0];
    f32x4* out4 = (f32x4*)d_out;

    const int threads = 256;
    const int blocks = (NQ_ALL / QT) * (NS_ALL / ST) * DIM0;  // 5*2*128 = 1280
    concat_pairs_lds_kernel<<<blocks, threads, 0, stream>>>(x4, out4);
}